// Round 6
// baseline (10.517 us; speedup 1.0000x reference)
//
#include <hip/hip_runtime.h>

// VQC 8 qubits, closed form via Pauli propagation (verified in round 5).
// Round 6: latency attack. Per sample, TWO waves: u=0 -> z0,z2,z4,z6,
// u=1 -> z1,z3,z5,z7 (wave-uniform split, 2 waves/SIMD). Weight trig
// (32 sincos) computed once per block by 16 lanes into LDS; per-thread
// transcendentals drop 80 -> 16. Algebra identical to round 5.

constexpr int NQ = 8;

__global__ __launch_bounds__(256) void vqc_closed2(
    const float* __restrict__ inputs,   // (B, 8) f32
    const float* __restrict__ weights,  // (2, 8) f32
    float* __restrict__ out,            // (B, 8) f32
    int B)
{
    __shared__ float W[32];   // cA[0..7] sA[0..7] cB[0..7] sB[0..7]

    const int tb = threadIdx.x;
    if (tb < 16) {
        float ss, cc;
        __sincosf(weights[tb], &ss, &cc);
        const int base = (tb >> 3) << 4;   // 0 for layer A, 16 for layer B
        const int off  = tb & 7;
        W[base + off]     = cc;
        W[base + 8 + off] = ss;
    }
    __syncthreads();

    const int sl     = tb & 127;           // sample slot within block
    const int u      = tb >> 7;            // 0: even outputs, 1: odd (per-wave)
    const int sample = blockIdx.x * 128 + sl;
    if (sample >= B) return;

    // ---- per-sample input trig ----
    const float4 a4 = ((const float4*)(inputs + (size_t)sample * NQ))[0];
    const float4 b4 = ((const float4*)(inputs + (size_t)sample * NQ))[1];
    const float xx[8] = {a4.x, a4.y, a4.z, a4.w, b4.x, b4.y, b4.z, b4.w};
    float sx[8], cx[8];
#pragma unroll
    for (int w = 0; w < 8; ++w) __sincosf(xx[w], &sx[w], &cx[w]);

    // ---- weight trig from LDS (broadcast reads) ----
    float cA[8], sA[8], cB[8], sB[8];
#pragma unroll
    for (int j = 0; j < 8; ++j) {
        cA[j] = W[j];      sA[j] = W[8 + j];
        cB[j] = W[16 + j]; sB[j] = W[24 + j];
    }

    float* o = out + (size_t)sample * NQ;

    if (u == 0) {
        // ---- even outputs: z0, z2, z4, z6 ----
        const float pA12 = cA[1]*cA[2], qA12 = sA[1]*sA[2];
        const float pA34 = cA[3]*cA[4], qA34 = sA[3]*sA[4];

        const float z0 = cx[0]*(cA[0]*cB[0] - sA[0]*sB[0]*sx[1]*sx[2]);

        const float z2 = cx[0]*cx[2]*cA[0]*( cA[1]*cA[2]*cB[2]
                       - sA[1]*sA[2]*cB[2]*sx[1]*sx[3]
                       - sA[1]*cA[2]*sB[2]*sx[1]*sx[4]
                       - cA[1]*sA[2]*sB[2]*sx[3]*sx[4] );

        const float z4 = cx[0]*cx[2]*cx[4]*cA[0]*(
              pA12*( cA[3]*cA[4]*cB[4]
                   - sA[3]*sA[4]*cB[4]*sx[3]*sx[5]
                   - sA[3]*cA[4]*sB[4]*sx[3]*sx[6]
                   - cA[3]*sA[4]*sB[4]*sx[5]*sx[6] )
            - qA12*( cA[3]*cA[4]*cB[4]*sx[1]*sx[3]
                   - sA[3]*sA[4]*cB[4]*sx[1]*sx[5]
                   - sA[3]*cA[4]*sB[4]*sx[1]*sx[6]
                   - cA[3]*sA[4]*sB[4]*sx[1]*sx[3]*sx[5]*sx[6] ) );

        const float z6 = cx[0]*cx[2]*cx[4]*cx[6]*cA[0]*(
              pA12*( pA34*( cA[5]*cA[6]*cB[6]
                          - sA[5]*sA[6]*cB[6]*sx[5]*sx[7]
                          - sA[5]*cA[6]*sB[6]*sx[5]
                          - cA[5]*sA[6]*sB[6]*sx[7] )
                  - qA34*( cA[5]*cA[6]*cB[6]*sx[3]*sx[5]
                          - sA[5]*sA[6]*cB[6]*sx[3]*sx[7]
                          - sA[5]*cA[6]*sB[6]*sx[3]
                          - cA[5]*sA[6]*sB[6]*sx[3]*sx[5]*sx[7] ) )
            - qA12*( pA34*( cA[5]*cA[6]*cB[6]*sx[1]*sx[3]
                          - sA[5]*sA[6]*cB[6]*sx[1]*sx[3]*sx[5]*sx[7]
                          - sA[5]*cA[6]*sB[6]*sx[1]*sx[3]*sx[5]
                          - cA[5]*sA[6]*sB[6]*sx[1]*sx[3]*sx[7] )
                  - qA34*( cA[5]*cA[6]*cB[6]*sx[1]*sx[5]
                          - sA[5]*sA[6]*cB[6]*sx[1]*sx[7]
                          - sA[5]*cA[6]*sB[6]*sx[1]
                          - cA[5]*sA[6]*sB[6]*sx[1]*sx[5]*sx[7] ) ) );

        o[0] = z0; o[2] = z2; o[4] = z4; o[6] = z6;
    } else {
        // ---- odd outputs: z1, z3, z5, z7 ----
        const float pA01 = cA[0]*cA[1], qA01 = sA[0]*sA[1];
        const float pA23 = cA[2]*cA[3], qA23 = sA[2]*sA[3];
        const float pA45 = cA[4]*cA[5], qA45 = sA[4]*sA[5];
        const float E7 = cA[6]*(cA[7]*cB[7] - sA[7]*sB[7]);
        const float O7 = -sA[6]*(sA[7]*cB[7] + cA[7]*sB[7]);

        const float z1 = cx[1]*( cA[0]*cA[1]*cB[1]
                       - sA[0]*sA[1]*cB[1]*sx[0]*sx[2]
                       - sA[0]*cA[1]*sB[1]*sx[0]*sx[3]
                       - cA[0]*sA[1]*sB[1]*sx[2]*sx[3] );

        const float z3 = cx[1]*cx[3]*(
              pA01*( cA[2]*cA[3]*cB[3]
                   - sA[2]*sA[3]*cB[3]*sx[2]*sx[4]
                   - sA[2]*cA[3]*sB[3]*sx[2]*sx[5]
                   - cA[2]*sA[3]*sB[3]*sx[4]*sx[5] )
            - qA01*( cA[2]*cA[3]*cB[3]*sx[0]*sx[2]
                   - sA[2]*sA[3]*cB[3]*sx[0]*sx[4]
                   - sA[2]*cA[3]*sB[3]*sx[0]*sx[5]
                   - cA[2]*sA[3]*sB[3]*sx[0]*sx[2]*sx[4]*sx[5] ) );

        const float z5 = cx[1]*cx[3]*cx[5]*(
              pA01*( pA23*( cA[4]*cA[5]*cB[5]
                          - sA[4]*sA[5]*cB[5]*sx[4]*sx[6]
                          - sA[4]*cA[5]*sB[5]*sx[4]*sx[7]
                          - cA[4]*sA[5]*sB[5]*sx[6]*sx[7] )
                  - qA23*( cA[4]*cA[5]*cB[5]*sx[2]*sx[4]
                          - sA[4]*sA[5]*cB[5]*sx[2]*sx[6]
                          - sA[4]*cA[5]*sB[5]*sx[2]*sx[7]
                          - cA[4]*sA[5]*sB[5]*sx[2]*sx[4]*sx[6]*sx[7] ) )
            - qA01*( pA23*( cA[4]*cA[5]*cB[5]*sx[0]*sx[2]
                          - sA[4]*sA[5]*cB[5]*sx[0]*sx[2]*sx[4]*sx[6]
                          - sA[4]*cA[5]*sB[5]*sx[0]*sx[2]*sx[4]*sx[7]
                          - cA[4]*sA[5]*sB[5]*sx[0]*sx[2]*sx[6]*sx[7] )
                  - qA23*( cA[4]*cA[5]*cB[5]*sx[0]*sx[4]
                          - sA[4]*sA[5]*cB[5]*sx[0]*sx[6]
                          - sA[4]*cA[5]*sB[5]*sx[0]*sx[7]
                          - cA[4]*sA[5]*sB[5]*sx[0]*sx[4]*sx[6]*sx[7] ) ) );

        const float z7 = cx[1]*cx[3]*cx[5]*cx[7]*(
              pA01*( pA23*( pA45*( E7 + O7*sx[6] )
                          - qA45*( E7*sx[4]*sx[6] + O7*sx[4] ) )
                  - qA23*( pA45*( E7*sx[2]*sx[4] + O7*sx[2]*sx[4]*sx[6] )
                          - qA45*( E7*sx[2]*sx[6] + O7*sx[2] ) ) )
            - qA01*( pA23*( pA45*( E7*sx[0]*sx[2] + O7*sx[0]*sx[2]*sx[6] )
                          - qA45*( E7*sx[0]*sx[2]*sx[4]*sx[6] + O7*sx[0]*sx[2]*sx[4] ) )
                  - qA23*( pA45*( E7*sx[0]*sx[4] + O7*sx[0]*sx[4]*sx[6] )
                          - qA45*( E7*sx[0]*sx[6] + O7*sx[0] ) ) ) );

        o[1] = z1; o[3] = z3; o[5] = z5; o[7] = z7;
    }
}

extern "C" void kernel_launch(void* const* d_in, const int* in_sizes, int n_in,
                              void* d_out, int out_size, void* d_ws, size_t ws_size,
                              hipStream_t stream) {
    const float* inputs  = (const float*)d_in[0];
    const float* weights = (const float*)d_in[1];
    float* out = (float*)d_out;
    const int B = in_sizes[0] / NQ;            // 65536
    const int blocks = (B + 127) / 128;        // 512 (128 samples x 2 waves each)
    vqc_closed2<<<blocks, 256, 0, stream>>>(inputs, weights, out, B);
}